// Round 15
// baseline (124.843 us; speedup 1.0000x reference)
//
#include <hip/hip_runtime.h>
#include <hip/hip_bf16.h>
#include <math.h>

#define NN 8192
#define NFEAT 1433
#define NHID 64
#define NCLASS 7
#define CAP 96

#define KSPLIT 4
#define KCHUNK 360        // 4*360 = 1440 >= 1433; up to 12 k-steps of 32 per chunk
#define NB_GEMM 512       // 128 tiles x 4 k-chunks
#define NB_SCAN 2048      // triangle-scan blocks: 4 rows each (1 row per wave)
#define NB_CSR 2048
#define NB_RED 512

typedef float f32x4 __attribute__((ext_vector_type(4)));
typedef short bf16x8 __attribute__((ext_vector_type(8)));

__device__ __forceinline__ ushort f2bf(float f) {
    __hip_bfloat16 h = __float2bfloat16(f);
    return *reinterpret_cast<ushort*>(&h);
}

// ---------------------------------------------------------------------------
// k_zero: zero the 8MB bitmask (~2us grid store).
// ---------------------------------------------------------------------------
__global__ __launch_bounds__(256) void k_zero(uint4* __restrict__ p) {
    p[(size_t)blockIdx.x * 256 + threadIdx.x] = make_uint4(0u, 0u, 0u, 0u);
}

// ---------------------------------------------------------------------------
// scan_row (R12-exact): stream cols [0,row) of one adjacency row, emit own
// bits via ballot-word stores (interior plain, boundary atomicOr) and mirror
// bits via one atomicOr per nonzero. Depth-4 rolling register prefetch.
// Bit layout (matches csr decode): col c -> word (c>>8)*4+(c&3), bit (c>>2)&63.
// ---------------------------------------------------------------------------
__device__ __forceinline__ void scan_row(const int row, const float* __restrict__ adj,
                                         unsigned long long* __restrict__ bmq,
                                         const int lane) {
    const int nq = (row + 255) >> 8;
    if (nq == 0) return;
    const int boundary = row >> 8;
    const f32x4* arow4 = (const f32x4*)(adj + (size_t)row * NN);
    unsigned long long* rowbm = bmq + (size_t)row * 128;
    const int mwidx = ((row >> 8) << 2) + (row & 3);
    const unsigned long long mbit = 1ull << ((row >> 2) & 63);

    f32x4 bufr[4];
    #pragma unroll
    for (int i = 0; i < 4; ++i)
        if (i < nq) bufr[i] = arow4[i * 64 + lane];

    for (int cbase = 0; cbase < nq; cbase += 4) {
        #pragma unroll
        for (int u = 0; u < 4; ++u) {
            const int c = cbase + u;
            if (c >= nq) break;
            f32x4 cur = bufr[u];
            if (c + 4 < nq) bufr[u] = arow4[(c + 4) * 64 + lane];

            const int colb = c * 256 + 4 * lane;
            bool nz0 = (cur[0] != 0.f) && (colb + 0 < row);
            bool nz1 = (cur[1] != 0.f) && (colb + 1 < row);
            bool nz2 = (cur[2] != 0.f) && (colb + 2 < row);
            bool nz3 = (cur[3] != 0.f) && (colb + 3 < row);
            unsigned long long m0 = __ballot(nz0);
            unsigned long long m1 = __ballot(nz1);
            unsigned long long m2 = __ballot(nz2);
            unsigned long long m3 = __ballot(nz3);
            unsigned long long w = (lane & 2) ? ((lane & 1) ? m3 : m2)
                                              : ((lane & 1) ? m1 : m0);
            if (c < boundary) {
                if (lane < 4) rowbm[c * 4 + lane] = w;
            } else {
                if (lane < 4 && w) atomicOr(&rowbm[c * 4 + lane], w);
            }
            if (nz0) atomicOr(&bmq[(size_t)(colb + 0) * 128 + mwidx], mbit);
            if (nz1) atomicOr(&bmq[(size_t)(colb + 1) * 128 + mwidx], mbit);
            if (nz2) atomicOr(&bmq[(size_t)(colb + 2) * 128 + mwidx], mbit);
            if (nz3) atomicOr(&bmq[(size_t)(colb + 3) * 128 + mwidx], mbit);
        }
    }
}

// ---------------------------------------------------------------------------
// K1: triangle scan role (2048 blocks, 1 row/wave, ascending — R12 exact) ||
// MFMA-gemm role (512 blocks, KSPLIT=4), interleaved 1:4 by blockIdx%5 so the
// scan gets 80% of resident waves (scan is MLP-limited: R13/R14 evidence).
// ---------------------------------------------------------------------------
__global__ __launch_bounds__(256, 8) void k1_scan_gemm(const float* __restrict__ adj,
                                                       const float* __restrict__ x,
                                                       const float* __restrict__ W1,
                                                       unsigned long long* __restrict__ bmq,
                                                       float* __restrict__ part) {
    __shared__ __align__(16) ushort xa[64][40];
    __shared__ __align__(16) ushort wt[64][40];

    const int t  = threadIdx.x;
    const int b  = blockIdx.x;
    const int r5 = b % 5;
    const int g5 = b / 5;

    if (r5 == 0) {
        // ----------------- GEMM role (MFMA bf16) ---------------------------
        const int tile = g5 >> 2;     // 0..127
        const int ks   = g5 & 3;      // 0..3
        const int m0 = tile * 64;
        const int k_begin = ks * KCHUNK;
        const int k_end   = (k_begin + KCHUNK < NFEAT) ? k_begin + KCHUNK : NFEAT;
        const int l = t & 63;
        const int w = t >> 6;

        const int sr  = t >> 2;
        const int sc8 = (t & 3) * 8;
        const float* xrow = x + (size_t)(m0 + sr) * NFEAT;
        const int wc  = t & 63;
        const int wk8 = (t >> 6) * 8;
        const int arow = w * 16 + (l & 15);
        const int kb   = (l >> 4) * 8;

        f32x4 acc[4];
        #pragma unroll
        for (int ct = 0; ct < 4; ++ct) acc[ct] = (f32x4){0.f, 0.f, 0.f, 0.f};

        for (int k0 = k_begin; k0 < k_end; k0 += 32) {
            uint4 xp;
            {
                ushort u[8];
                #pragma unroll
                for (int jj = 0; jj < 8; ++jj) {
                    int k = k0 + sc8 + jj;
                    u[jj] = f2bf((k < k_end) ? xrow[k] : 0.f);
                }
                xp.x = (unsigned)u[0] | ((unsigned)u[1] << 16);
                xp.y = (unsigned)u[2] | ((unsigned)u[3] << 16);
                xp.z = (unsigned)u[4] | ((unsigned)u[5] << 16);
                xp.w = (unsigned)u[6] | ((unsigned)u[7] << 16);
            }
            *(uint4*)(&xa[sr][sc8]) = xp;
            uint4 wp;
            {
                ushort u[8];
                #pragma unroll
                for (int jj = 0; jj < 8; ++jj) {
                    int k = k0 + wk8 + jj;
                    u[jj] = f2bf((k < k_end) ? W1[(size_t)k * 64 + wc] : 0.f);
                }
                wp.x = (unsigned)u[0] | ((unsigned)u[1] << 16);
                wp.y = (unsigned)u[2] | ((unsigned)u[3] << 16);
                wp.z = (unsigned)u[4] | ((unsigned)u[5] << 16);
                wp.w = (unsigned)u[6] | ((unsigned)u[7] << 16);
            }
            *(uint4*)(&wt[wc][wk8]) = wp;
            __syncthreads();

            bf16x8 af = *(const bf16x8*)(&xa[arow][kb]);
            #pragma unroll
            for (int ct = 0; ct < 4; ++ct) {
                bf16x8 bfr = *(const bf16x8*)(&wt[ct * 16 + (l & 15)][kb]);
                acc[ct] = __builtin_amdgcn_mfma_f32_16x16x32_bf16(af, bfr, acc[ct], 0, 0, 0);
            }
            __syncthreads();
        }
        float* pout = part + (size_t)ks * NN * NHID;
        const int orow = m0 + w * 16 + ((l >> 4) << 2);
        const int ocol = l & 15;
        #pragma unroll
        for (int ct = 0; ct < 4; ++ct)
            #pragma unroll
            for (int rix = 0; rix < 4; ++rix)
                pout[(size_t)(orow + rix) * 64 + ct * 16 + ocol] = acc[ct][rix];
    } else {
        // ----------------- triangle scan role: 1 row per wave --------------
        const int wave = t >> 6;
        const int lane = t & 63;
        const int bid  = g5 * 4 + (r5 - 1);     // 0..2047
        const int row  = bid * 4 + wave;        // ascending (R12 exact)
        scan_row(row, adj, bmq, lane);
    }
}

// ---------------------------------------------------------------------------
// K2: csr role (2048 blocks) || reduce role (512 blocks). KSPLIT=4 reduce.
// ---------------------------------------------------------------------------
__global__ __launch_bounds__(256) void k2_csr_reduce(const unsigned long long* __restrict__ bmq,
                                                     const float* __restrict__ P,
                                                     const float* __restrict__ part,
                                                     int* __restrict__ cnt,
                                                     int* __restrict__ cols,
                                                     float* __restrict__ vals,
                                                     float* __restrict__ dinv,
                                                     float* __restrict__ XW1) {
    const int b = blockIdx.x;
    if (b >= NB_CSR) {
        const size_t i4 = (size_t)(b - NB_CSR) * 256 + threadIdx.x;
        const f32x4* p4 = (const f32x4*)part;
        f32x4 s = p4[i4];
        #pragma unroll
        for (int ks = 1; ks < KSPLIT; ++ks)
            s += p4[(size_t)ks * (NN * NHID / 4) + i4];
        ((f32x4*)XW1)[i4] = s;
        return;
    }
    const int wave = threadIdx.x >> 6;
    const int lane = threadIdx.x & 63;
    const int row  = b * 4 + wave;

    const unsigned long long* rw = bmq + (size_t)row * 128;
    unsigned long long w0 = rw[2 * lane];
    unsigned long long w1 = rw[2 * lane + 1];
    const int myc = __popcll(w0) + __popcll(w1);

    int incl = myc;
    #pragma unroll
    for (int ofs = 1; ofs < 64; ofs <<= 1) {
        int y = __shfl_up(incl, ofs, 64);
        if (lane >= ofs) incl += y;
    }
    const int total = __shfl(incl, 63, 64);
    int pos = incl - myc;

    const size_t rowCAP = (size_t)row * CAP;
    float dsum = 0.f;
    #pragma unroll
    for (int i = 0; i < 2; ++i) {
        unsigned long long w = i ? w1 : w0;
        const int widx = 2 * lane + i;
        const int Cl = widx >> 2, s = widx & 3;
        const int colbase = 256 * Cl + s;
        while (w) {
            int j = __builtin_ctzll(w);
            w &= w - 1;
            int col = colbase + 4 * j;
            unsigned lo = (col <= row) ? (unsigned)col : (unsigned)row;
            unsigned hi = (col <= row) ? (unsigned)row : (unsigned)col;
            unsigned pidx = hi * (hi + 1u) / 2u + lo;
            float p = P[pidx];
            float v = 1.f / (1.f + __expf(-p));
            if (pos < CAP) {
                cols[rowCAP + pos] = col;
                vals[rowCAP + pos] = v;
            }
            dsum += v;
            ++pos;
        }
    }
    #pragma unroll
    for (int s2 = 32; s2; s2 >>= 1) dsum += __shfl_xor(dsum, s2, 64);
    if (lane == 0) {
        cnt[row]  = (total < CAP) ? total : CAP;
        dinv[row] = 1.f / sqrtf(1.f + dsum);
    }
}

// ---------------------------------------------------------------------------
// spmm1 (unchanged)
// ---------------------------------------------------------------------------
__global__ __launch_bounds__(256) void k_spmm1(const float* __restrict__ XW1,
                                               const float* __restrict__ dinv,
                                               const int* __restrict__ cnt,
                                               const int* __restrict__ cols,
                                               const float* __restrict__ vals,
                                               const float* __restrict__ b1,
                                               const float* __restrict__ W2,
                                               float* __restrict__ HW2) {
    const int wave = threadIdx.x >> 6;
    const int lane = threadIdx.x & 63;
    const int row  = blockIdx.x * 4 + wave;
    if (row >= NN) return;

    const float di = dinv[row];
    float acc = di * XW1[(size_t)row * NHID + lane];
    const int c = cnt[row];
    const int*   cp = cols + (size_t)row * CAP;
    const float* vp = vals + (size_t)row * CAP;

    int j0 = 0, j1 = 0; float v0 = 0.f, v1 = 0.f, w0 = 0.f, w1 = 0.f, d0 = 0.f, d1 = 0.f;
    if (c > 0) { j0 = cp[0]; v0 = vp[0]; w0 = XW1[(size_t)j0 * NHID + lane]; d0 = dinv[j0]; }
    if (c > 1) { j1 = cp[1]; v1 = vp[1]; w1 = XW1[(size_t)j1 * NHID + lane]; d1 = dinv[j1]; }
    for (int k = 0; k < c; ++k) {
        acc += v0 * d0 * w0;
        j0 = j1; v0 = v1; w0 = w1; d0 = d1;
        if (k + 2 < c) {
            int jn = cp[k + 2];
            j1 = jn; v1 = vp[k + 2];
            w1 = XW1[(size_t)jn * NHID + lane];
            d1 = dinv[jn];
        }
    }
    float h1 = di * acc + b1[lane];
    h1 = fmaxf(h1, 0.f);

    float o[NCLASS];
    #pragma unroll
    for (int cc = 0; cc < NCLASS; ++cc) o[cc] = h1 * W2[lane * NCLASS + cc];
    #pragma unroll
    for (int cc = 0; cc < NCLASS; ++cc)
        for (int s = 32; s; s >>= 1) o[cc] += __shfl_xor(o[cc], s, 64);
    if (lane == 0) {
        #pragma unroll
        for (int cc = 0; cc < NCLASS; ++cc)
            HW2[(size_t)row * NCLASS + cc] = o[cc];
    }
}

// ---------------------------------------------------------------------------
// spmm2 (unchanged)
// ---------------------------------------------------------------------------
__global__ __launch_bounds__(256) void k_spmm2(const float* __restrict__ HW2,
                                               const float* __restrict__ dinv,
                                               const int* __restrict__ cnt,
                                               const int* __restrict__ cols,
                                               const float* __restrict__ vals,
                                               const float* __restrict__ b2,
                                               float* __restrict__ out) {
    const int wave = threadIdx.x >> 6;
    const int lane = threadIdx.x & 63;
    const int row  = blockIdx.x * 4 + wave;
    if (row >= NN) return;

    const int c = cnt[row];
    const int*   cp = cols + (size_t)row * CAP;
    const float* vp = vals + (size_t)row * CAP;
    float acc[NCLASS] = {};
    for (int k = lane; k < c; k += 64) {
        int j   = cp[k];
        float wgt = vp[k] * dinv[j];
        #pragma unroll
        for (int cc = 0; cc < NCLASS; ++cc)
            acc[cc] += wgt * HW2[(size_t)j * NCLASS + cc];
    }
    #pragma unroll
    for (int cc = 0; cc < NCLASS; ++cc)
        for (int s = 32; s; s >>= 1) acc[cc] += __shfl_xor(acc[cc], s, 64);

    if (lane == 0) {
        const float di = dinv[row];
        float h[NCLASS], m = -1e30f;
        #pragma unroll
        for (int cc = 0; cc < NCLASS; ++cc) {
            h[cc] = di * (acc[cc] + di * HW2[(size_t)row * NCLASS + cc]) + b2[cc];
            m = fmaxf(m, h[cc]);
        }
        float s = 0.f;
        #pragma unroll
        for (int cc = 0; cc < NCLASS; ++cc) s += expf(h[cc] - m);
        float lse = m + logf(s);
        #pragma unroll
        for (int cc = 0; cc < NCLASS; ++cc)
            out[(size_t)row * NCLASS + cc] = h[cc] - lse;
    }
}

// ---------------------------------------------------------------------------
extern "C" void kernel_launch(void* const* d_in, const int* in_sizes, int n_in,
                              void* d_out, int out_size, void* d_ws, size_t ws_size,
                              hipStream_t stream) {
    const float* x   = (const float*)d_in[0];
    const float* adj = (const float*)d_in[1];
    const float* P   = (const float*)d_in[2];
    const float* W1  = (const float*)d_in[3];
    const float* b1  = (const float*)d_in[4];
    const float* W2  = (const float*)d_in[5];
    const float* b2  = (const float*)d_in[6];
    float* out = (float*)d_out;

    char* ws = (char*)d_ws;
    size_t off = 0;
    float* dinv = (float*)(ws + off);  off += (size_t)NN * 4;
    int*   cnt  = (int*)  (ws + off);  off += (size_t)NN * 4;
    int*   cols = (int*)  (ws + off);  off += (size_t)NN * CAP * 4;
    float* vals = (float*)(ws + off);  off += (size_t)NN * CAP * 4;
    float* XW1  = (float*)(ws + off);  off += (size_t)NN * NHID * 4;
    float* HW2  = (float*)(ws + off);  off += (size_t)NN * NCLASS * 4;
    float* part = (float*)(ws + off);  off += (size_t)KSPLIT * NN * NHID * 4;
    off = (off + 255) & ~(size_t)255;
    unsigned long long* bmq = (unsigned long long*)(ws + off);
    off += (size_t)NN * 128 * 8;   // 8 MB bitmask

    k_zero<<<dim3(2048), dim3(256), 0, stream>>>((uint4*)bmq);
    k1_scan_gemm<<<dim3(NB_GEMM + NB_SCAN + 0), dim3(256), 0, stream>>>(adj, x, W1, bmq, part);
    k2_csr_reduce<<<dim3(NB_CSR + NB_RED), dim3(256), 0, stream>>>(bmq, P, part,
                                                                   cnt, cols, vals, dinv, XW1);
    k_spmm1<<<dim3(NN / 4), dim3(256), 0, stream>>>(XW1, dinv, cnt, cols, vals, b1, W2, HW2);
    k_spmm2<<<dim3(NN / 4), dim3(256), 0, stream>>>(HW2, dinv, cnt, cols, vals, b2, out);
}

// Round 16
// 118.478 us; speedup vs baseline: 1.0537x; 1.0537x over previous
//
#include <hip/hip_runtime.h>
#include <hip/hip_bf16.h>
#include <math.h>

#define NN 8192
#define NFEAT 1433
#define NHID 64
#define NCLASS 7
#define CAP 96

#define KSPLIT 8
#define KCHUNK 192        // 8*192 = 1536 >= 1433; up to 6 k-steps of 32 per chunk
#define NB_GEMM 1024      // 128 tiles x 8 k-chunks
#define NB_SCAN 4096      // striped scan: 4 waves/block, 2 stripes per row
#define NB_CSR 2048
#define NB_RED 512

typedef float f32x4 __attribute__((ext_vector_type(4)));
typedef short bf16x8 __attribute__((ext_vector_type(8)));

__device__ __forceinline__ ushort f2bf(float f) {
    __hip_bfloat16 h = __float2bfloat16(f);
    return *reinterpret_cast<ushort*>(&h);
}

// ---------------------------------------------------------------------------
// k_zero: zero the 8MB bitmask (~2us grid store).
// ---------------------------------------------------------------------------
__global__ __launch_bounds__(256) void k_zero(uint4* __restrict__ p) {
    p[(size_t)blockIdx.x * 256 + threadIdx.x] = make_uint4(0u, 0u, 0u, 0u);
}

// ---------------------------------------------------------------------------
// scan_stripe: stream a 16-chunk (4096-col) stripe of one adjacency row's
// triangle part, emitting own bits (ballot words; interior plain stores,
// boundary chunk atomicOr) and mirror bits (one atomicOr per nonzero).
// Stripes of the same row are handled by DIFFERENT waves — bitmask words are
// disjoint so no coupling. Depth-4 rolling register prefetch (R12-proven).
// Bit layout (matches csr decode): col c -> word (c>>8)*4+(c&3), bit (c>>2)&63.
// ---------------------------------------------------------------------------
__device__ __forceinline__ void scan_stripe(const int row, const int stripe,
                                            const float* __restrict__ adj,
                                            unsigned long long* __restrict__ bmq,
                                            const int lane) {
    const int nq = (row + 255) >> 8;          // chunks covering cols [0,row)
    const int cs = stripe * 16;
    const int ce = (cs + 16 < nq) ? cs + 16 : nq;
    if (ce <= cs) return;
    const int boundary = row >> 8;
    const f32x4* arow4 = (const f32x4*)(adj + (size_t)row * NN);
    unsigned long long* rowbm = bmq + (size_t)row * 128;
    const int mwidx = ((row >> 8) << 2) + (row & 3);
    const unsigned long long mbit = 1ull << ((row >> 2) & 63);

    f32x4 bufr[4];
    #pragma unroll
    for (int i = 0; i < 4; ++i)
        if (cs + i < ce) bufr[i] = arow4[(cs + i) * 64 + lane];

    for (int cbase = cs; cbase < ce; cbase += 4) {
        #pragma unroll
        for (int u = 0; u < 4; ++u) {
            const int c = cbase + u;
            if (c >= ce) break;
            f32x4 cur = bufr[u];
            if (c + 4 < ce) bufr[u] = arow4[(c + 4) * 64 + lane];

            const int colb = c * 256 + 4 * lane;
            bool nz0 = (cur[0] != 0.f) && (colb + 0 < row);
            bool nz1 = (cur[1] != 0.f) && (colb + 1 < row);
            bool nz2 = (cur[2] != 0.f) && (colb + 2 < row);
            bool nz3 = (cur[3] != 0.f) && (colb + 3 < row);
            unsigned long long m0 = __ballot(nz0);
            unsigned long long m1 = __ballot(nz1);
            unsigned long long m2 = __ballot(nz2);
            unsigned long long m3 = __ballot(nz3);
            unsigned long long w = (lane & 2) ? ((lane & 1) ? m3 : m2)
                                              : ((lane & 1) ? m1 : m0);
            if (c < boundary) {
                if (lane < 4) rowbm[c * 4 + lane] = w;
            } else {
                if (lane < 4 && w) atomicOr(&rowbm[c * 4 + lane], w);
            }
            if (nz0) atomicOr(&bmq[(size_t)(colb + 0) * 128 + mwidx], mbit);
            if (nz1) atomicOr(&bmq[(size_t)(colb + 1) * 128 + mwidx], mbit);
            if (nz2) atomicOr(&bmq[(size_t)(colb + 2) * 128 + mwidx], mbit);
            if (nz3) atomicOr(&bmq[(size_t)(colb + 3) * 128 + mwidx], mbit);
        }
    }
}

// ---------------------------------------------------------------------------
// K1: striped triangle scan role (4096 blocks: 16384 waves = 8192 rows x 2
// stripes — 2x the independent wave-streams of R12, each half as long) ||
// MFMA-gemm role (1024 blocks, KSPLIT=8, R12-exact), interleaved by b%5.
// ---------------------------------------------------------------------------
__global__ __launch_bounds__(256, 8) void k1_scan_gemm(const float* __restrict__ adj,
                                                       const float* __restrict__ x,
                                                       const float* __restrict__ W1,
                                                       unsigned long long* __restrict__ bmq,
                                                       float* __restrict__ part) {
    __shared__ __align__(16) ushort xa[64][40];
    __shared__ __align__(16) ushort wt[64][40];

    const int t  = threadIdx.x;
    const int b  = blockIdx.x;
    const int r5 = b % 5;
    const int g5 = b / 5;

    if (r5 == 0) {
        // ----------------- GEMM role (MFMA bf16, R12-exact) ----------------
        const int tile = g5 >> 3;     // 0..127
        const int ks   = g5 & 7;      // 0..7
        const int m0 = tile * 64;
        const int k_begin = ks * KCHUNK;
        const int k_end   = (k_begin + KCHUNK < NFEAT) ? k_begin + KCHUNK : NFEAT;
        const int l = t & 63;
        const int w = t >> 6;

        const int sr  = t >> 2;
        const int sc8 = (t & 3) * 8;
        const float* xrow = x + (size_t)(m0 + sr) * NFEAT;
        const int wc  = t & 63;
        const int wk8 = (t >> 6) * 8;
        const int arow = w * 16 + (l & 15);
        const int kb   = (l >> 4) * 8;

        f32x4 acc[4];
        #pragma unroll
        for (int ct = 0; ct < 4; ++ct) acc[ct] = (f32x4){0.f, 0.f, 0.f, 0.f};

        for (int k0 = k_begin; k0 < k_end; k0 += 32) {
            uint4 xp;
            {
                ushort u[8];
                #pragma unroll
                for (int jj = 0; jj < 8; ++jj) {
                    int k = k0 + sc8 + jj;
                    u[jj] = f2bf((k < k_end) ? xrow[k] : 0.f);
                }
                xp.x = (unsigned)u[0] | ((unsigned)u[1] << 16);
                xp.y = (unsigned)u[2] | ((unsigned)u[3] << 16);
                xp.z = (unsigned)u[4] | ((unsigned)u[5] << 16);
                xp.w = (unsigned)u[6] | ((unsigned)u[7] << 16);
            }
            *(uint4*)(&xa[sr][sc8]) = xp;
            uint4 wp;
            {
                ushort u[8];
                #pragma unroll
                for (int jj = 0; jj < 8; ++jj) {
                    int k = k0 + wk8 + jj;
                    u[jj] = f2bf((k < k_end) ? W1[(size_t)k * 64 + wc] : 0.f);
                }
                wp.x = (unsigned)u[0] | ((unsigned)u[1] << 16);
                wp.y = (unsigned)u[2] | ((unsigned)u[3] << 16);
                wp.z = (unsigned)u[4] | ((unsigned)u[5] << 16);
                wp.w = (unsigned)u[6] | ((unsigned)u[7] << 16);
            }
            *(uint4*)(&wt[wc][wk8]) = wp;
            __syncthreads();

            bf16x8 af = *(const bf16x8*)(&xa[arow][kb]);
            #pragma unroll
            for (int ct = 0; ct < 4; ++ct) {
                bf16x8 bfr = *(const bf16x8*)(&wt[ct * 16 + (l & 15)][kb]);
                acc[ct] = __builtin_amdgcn_mfma_f32_16x16x32_bf16(af, bfr, acc[ct], 0, 0, 0);
            }
            __syncthreads();
        }
        float* pout = part + (size_t)ks * NN * NHID;
        const int orow = m0 + w * 16 + ((l >> 4) << 2);
        const int ocol = l & 15;
        #pragma unroll
        for (int ct = 0; ct < 4; ++ct)
            #pragma unroll
            for (int rix = 0; rix < 4; ++rix)
                pout[(size_t)(orow + rix) * 64 + ct * 16 + ocol] = acc[ct][rix];
    } else {
        // ----------------- striped scan role: 1 stripe per wave ------------
        const int wave = t >> 6;
        const int lane = t & 63;
        const int bid  = g5 * 4 + (r5 - 1);      // 0..4095
        const int wid  = bid * 4 + wave;         // 0..16383
        const int row    = wid >> 1;             // 0..8191
        const int stripe = wid & 1;              // 0..1
        scan_stripe(row, stripe, adj, bmq, lane);
    }
}

// ---------------------------------------------------------------------------
// K2: csr role (2048 blocks) || reduce role (512 blocks). R12-exact.
// ---------------------------------------------------------------------------
__global__ __launch_bounds__(256) void k2_csr_reduce(const unsigned long long* __restrict__ bmq,
                                                     const float* __restrict__ P,
                                                     const float* __restrict__ part,
                                                     int* __restrict__ cnt,
                                                     int* __restrict__ cols,
                                                     float* __restrict__ vals,
                                                     float* __restrict__ dinv,
                                                     float* __restrict__ XW1) {
    const int b = blockIdx.x;
    if (b >= NB_CSR) {
        const size_t i4 = (size_t)(b - NB_CSR) * 256 + threadIdx.x;
        const f32x4* p4 = (const f32x4*)part;
        f32x4 s = p4[i4];
        #pragma unroll
        for (int ks = 1; ks < KSPLIT; ++ks)
            s += p4[(size_t)ks * (NN * NHID / 4) + i4];
        ((f32x4*)XW1)[i4] = s;
        return;
    }
    const int wave = threadIdx.x >> 6;
    const int lane = threadIdx.x & 63;
    const int row  = b * 4 + wave;

    const unsigned long long* rw = bmq + (size_t)row * 128;
    unsigned long long w0 = rw[2 * lane];
    unsigned long long w1 = rw[2 * lane + 1];
    const int myc = __popcll(w0) + __popcll(w1);

    int incl = myc;
    #pragma unroll
    for (int ofs = 1; ofs < 64; ofs <<= 1) {
        int y = __shfl_up(incl, ofs, 64);
        if (lane >= ofs) incl += y;
    }
    const int total = __shfl(incl, 63, 64);
    int pos = incl - myc;

    const size_t rowCAP = (size_t)row * CAP;
    float dsum = 0.f;
    #pragma unroll
    for (int i = 0; i < 2; ++i) {
        unsigned long long w = i ? w1 : w0;
        const int widx = 2 * lane + i;
        const int Cl = widx >> 2, s = widx & 3;
        const int colbase = 256 * Cl + s;
        while (w) {
            int j = __builtin_ctzll(w);
            w &= w - 1;
            int col = colbase + 4 * j;
            unsigned lo = (col <= row) ? (unsigned)col : (unsigned)row;
            unsigned hi = (col <= row) ? (unsigned)row : (unsigned)col;
            unsigned pidx = hi * (hi + 1u) / 2u + lo;
            float p = P[pidx];
            float v = 1.f / (1.f + __expf(-p));
            if (pos < CAP) {
                cols[rowCAP + pos] = col;
                vals[rowCAP + pos] = v;
            }
            dsum += v;
            ++pos;
        }
    }
    #pragma unroll
    for (int s2 = 32; s2; s2 >>= 1) dsum += __shfl_xor(dsum, s2, 64);
    if (lane == 0) {
        cnt[row]  = (total < CAP) ? total : CAP;
        dinv[row] = 1.f / sqrtf(1.f + dsum);
    }
}

// ---------------------------------------------------------------------------
// spmm1 (unchanged)
// ---------------------------------------------------------------------------
__global__ __launch_bounds__(256) void k_spmm1(const float* __restrict__ XW1,
                                               const float* __restrict__ dinv,
                                               const int* __restrict__ cnt,
                                               const int* __restrict__ cols,
                                               const float* __restrict__ vals,
                                               const float* __restrict__ b1,
                                               const float* __restrict__ W2,
                                               float* __restrict__ HW2) {
    const int wave = threadIdx.x >> 6;
    const int lane = threadIdx.x & 63;
    const int row  = blockIdx.x * 4 + wave;
    if (row >= NN) return;

    const float di = dinv[row];
    float acc = di * XW1[(size_t)row * NHID + lane];
    const int c = cnt[row];
    const int*   cp = cols + (size_t)row * CAP;
    const float* vp = vals + (size_t)row * CAP;

    int j0 = 0, j1 = 0; float v0 = 0.f, v1 = 0.f, w0 = 0.f, w1 = 0.f, d0 = 0.f, d1 = 0.f;
    if (c > 0) { j0 = cp[0]; v0 = vp[0]; w0 = XW1[(size_t)j0 * NHID + lane]; d0 = dinv[j0]; }
    if (c > 1) { j1 = cp[1]; v1 = vp[1]; w1 = XW1[(size_t)j1 * NHID + lane]; d1 = dinv[j1]; }
    for (int k = 0; k < c; ++k) {
        acc += v0 * d0 * w0;
        j0 = j1; v0 = v1; w0 = w1; d0 = d1;
        if (k + 2 < c) {
            int jn = cp[k + 2];
            j1 = jn; v1 = vp[k + 2];
            w1 = XW1[(size_t)jn * NHID + lane];
            d1 = dinv[jn];
        }
    }
    float h1 = di * acc + b1[lane];
    h1 = fmaxf(h1, 0.f);

    float o[NCLASS];
    #pragma unroll
    for (int cc = 0; cc < NCLASS; ++cc) o[cc] = h1 * W2[lane * NCLASS + cc];
    #pragma unroll
    for (int cc = 0; cc < NCLASS; ++cc)
        for (int s = 32; s; s >>= 1) o[cc] += __shfl_xor(o[cc], s, 64);
    if (lane == 0) {
        #pragma unroll
        for (int cc = 0; cc < NCLASS; ++cc)
            HW2[(size_t)row * NCLASS + cc] = o[cc];
    }
}

// ---------------------------------------------------------------------------
// spmm2 (unchanged)
// ---------------------------------------------------------------------------
__global__ __launch_bounds__(256) void k_spmm2(const float* __restrict__ HW2,
                                               const float* __restrict__ dinv,
                                               const int* __restrict__ cnt,
                                               const int* __restrict__ cols,
                                               const float* __restrict__ vals,
                                               const float* __restrict__ b2,
                                               float* __restrict__ out) {
    const int wave = threadIdx.x >> 6;
    const int lane = threadIdx.x & 63;
    const int row  = blockIdx.x * 4 + wave;
    if (row >= NN) return;

    const int c = cnt[row];
    const int*   cp = cols + (size_t)row * CAP;
    const float* vp = vals + (size_t)row * CAP;
    float acc[NCLASS] = {};
    for (int k = lane; k < c; k += 64) {
        int j   = cp[k];
        float wgt = vp[k] * dinv[j];
        #pragma unroll
        for (int cc = 0; cc < NCLASS; ++cc)
            acc[cc] += wgt * HW2[(size_t)j * NCLASS + cc];
    }
    #pragma unroll
    for (int cc = 0; cc < NCLASS; ++cc)
        for (int s = 32; s; s >>= 1) acc[cc] += __shfl_xor(acc[cc], s, 64);

    if (lane == 0) {
        const float di = dinv[row];
        float h[NCLASS], m = -1e30f;
        #pragma unroll
        for (int cc = 0; cc < NCLASS; ++cc) {
            h[cc] = di * (acc[cc] + di * HW2[(size_t)row * NCLASS + cc]) + b2[cc];
            m = fmaxf(m, h[cc]);
        }
        float s = 0.f;
        #pragma unroll
        for (int cc = 0; cc < NCLASS; ++cc) s += expf(h[cc] - m);
        float lse = m + logf(s);
        #pragma unroll
        for (int cc = 0; cc < NCLASS; ++cc)
            out[(size_t)row * NCLASS + cc] = h[cc] - lse;
    }
}

// ---------------------------------------------------------------------------
extern "C" void kernel_launch(void* const* d_in, const int* in_sizes, int n_in,
                              void* d_out, int out_size, void* d_ws, size_t ws_size,
                              hipStream_t stream) {
    const float* x   = (const float*)d_in[0];
    const float* adj = (const float*)d_in[1];
    const float* P   = (const float*)d_in[2];
    const float* W1  = (const float*)d_in[3];
    const float* b1  = (const float*)d_in[4];
    const float* W2  = (const float*)d_in[5];
    const float* b2  = (const float*)d_in[6];
    float* out = (float*)d_out;

    char* ws = (char*)d_ws;
    size_t off = 0;
    float* dinv = (float*)(ws + off);  off += (size_t)NN * 4;
    int*   cnt  = (int*)  (ws + off);  off += (size_t)NN * 4;
    int*   cols = (int*)  (ws + off);  off += (size_t)NN * CAP * 4;
    float* vals = (float*)(ws + off);  off += (size_t)NN * CAP * 4;
    float* XW1  = (float*)(ws + off);  off += (size_t)NN * NHID * 4;
    float* HW2  = (float*)(ws + off);  off += (size_t)NN * NCLASS * 4;
    float* part = (float*)(ws + off);  off += (size_t)KSPLIT * NN * NHID * 4;
    off = (off + 255) & ~(size_t)255;
    unsigned long long* bmq = (unsigned long long*)(ws + off);
    off += (size_t)NN * 128 * 8;   // 8 MB bitmask

    k_zero<<<dim3(2048), dim3(256), 0, stream>>>((uint4*)bmq);
    k1_scan_gemm<<<dim3(NB_GEMM + NB_SCAN), dim3(256), 0, stream>>>(adj, x, W1, bmq, part);
    k2_csr_reduce<<<dim3(NB_CSR + NB_RED), dim3(256), 0, stream>>>(bmq, P, part,
                                                                   cnt, cols, vals, dinv, XW1);
    k_spmm1<<<dim3(NN / 4), dim3(256), 0, stream>>>(XW1, dinv, cnt, cols, vals, b1, W2, HW2);
    k_spmm2<<<dim3(NN / 4), dim3(256), 0, stream>>>(HW2, dinv, cnt, cols, vals, b2, out);
}

// Round 17
// 107.577 us; speedup vs baseline: 1.1605x; 1.1013x over previous
//
#include <hip/hip_runtime.h>
#include <hip/hip_bf16.h>
#include <math.h>

#define NN 8192
#define NFEAT 1433
#define NHID 64
#define NCLASS 7
#define CAP 96

#define KSPLIT 8
#define KCHUNK 192        // 8*192 = 1536 >= 1433; up to 6 k-steps of 32 per chunk
#define NB_GEMM 1024      // 128 tiles x 8 k-chunks — blocks [0, 1024): resident at t=0
#define NB_SCAN 2048      // triangle-scan blocks: 4 rows each (1 row per wave)
#define NB_CSR 2048
#define NB_RED 512

typedef float f32x4 __attribute__((ext_vector_type(4)));
typedef short bf16x8 __attribute__((ext_vector_type(8)));

__device__ __forceinline__ ushort f2bf(float f) {
    __hip_bfloat16 h = __float2bfloat16(f);
    return *reinterpret_cast<ushort*>(&h);
}

// ---------------------------------------------------------------------------
// k_zero: zero the 8MB bitmask (~2us grid store).
// ---------------------------------------------------------------------------
__global__ __launch_bounds__(256) void k_zero(uint4* __restrict__ p) {
    p[(size_t)blockIdx.x * 256 + threadIdx.x] = make_uint4(0u, 0u, 0u, 0u);
}

// ---------------------------------------------------------------------------
// scan_row (R12-exact): stream cols [0,row) of one adjacency row, emit own
// bits via ballot-word stores (interior plain, boundary atomicOr) and mirror
// bits via one atomicOr per nonzero. Depth-4 rolling register prefetch.
// Bit layout (matches csr decode): col c -> word (c>>8)*4+(c&3), bit (c>>2)&63.
// ---------------------------------------------------------------------------
__device__ __forceinline__ void scan_row(const int row, const float* __restrict__ adj,
                                         unsigned long long* __restrict__ bmq,
                                         const int lane) {
    const int nq = (row + 255) >> 8;
    if (nq == 0) return;
    const int boundary = row >> 8;
    const f32x4* arow4 = (const f32x4*)(adj + (size_t)row * NN);
    unsigned long long* rowbm = bmq + (size_t)row * 128;
    const int mwidx = ((row >> 8) << 2) + (row & 3);
    const unsigned long long mbit = 1ull << ((row >> 2) & 63);

    f32x4 bufr[4];
    #pragma unroll
    for (int i = 0; i < 4; ++i)
        if (i < nq) bufr[i] = arow4[i * 64 + lane];

    for (int cbase = 0; cbase < nq; cbase += 4) {
        #pragma unroll
        for (int u = 0; u < 4; ++u) {
            const int c = cbase + u;
            if (c >= nq) break;
            f32x4 cur = bufr[u];
            if (c + 4 < nq) bufr[u] = arow4[(c + 4) * 64 + lane];

            const int colb = c * 256 + 4 * lane;
            bool nz0 = (cur[0] != 0.f) && (colb + 0 < row);
            bool nz1 = (cur[1] != 0.f) && (colb + 1 < row);
            bool nz2 = (cur[2] != 0.f) && (colb + 2 < row);
            bool nz3 = (cur[3] != 0.f) && (colb + 3 < row);
            unsigned long long m0 = __ballot(nz0);
            unsigned long long m1 = __ballot(nz1);
            unsigned long long m2 = __ballot(nz2);
            unsigned long long m3 = __ballot(nz3);
            unsigned long long w = (lane & 2) ? ((lane & 1) ? m3 : m2)
                                              : ((lane & 1) ? m1 : m0);
            if (c < boundary) {
                if (lane < 4) rowbm[c * 4 + lane] = w;
            } else {
                if (lane < 4 && w) atomicOr(&rowbm[c * 4 + lane], w);
            }
            if (nz0) atomicOr(&bmq[(size_t)(colb + 0) * 128 + mwidx], mbit);
            if (nz1) atomicOr(&bmq[(size_t)(colb + 1) * 128 + mwidx], mbit);
            if (nz2) atomicOr(&bmq[(size_t)(colb + 2) * 128 + mwidx], mbit);
            if (nz3) atomicOr(&bmq[(size_t)(colb + 3) * 128 + mwidx], mbit);
        }
    }
}

// ---------------------------------------------------------------------------
// K1: GEMM role = blocks [0, NB_GEMM) — dispatched FIRST so all MFMA work is
// resident from t=0 and finishes inside the scan window (kills the late-GEMM
// tail of the mod-3 interleave). Scan role = blocks [NB_GEMM, NB_GEMM+NB_SCAN),
// 1 row/wave ascending (R12-exact internals).
// ---------------------------------------------------------------------------
__global__ __launch_bounds__(256, 8) void k1_scan_gemm(const float* __restrict__ adj,
                                                       const float* __restrict__ x,
                                                       const float* __restrict__ W1,
                                                       unsigned long long* __restrict__ bmq,
                                                       float* __restrict__ part) {
    __shared__ __align__(16) ushort xa[64][40];
    __shared__ __align__(16) ushort wt[64][40];

    const int t = threadIdx.x;
    const int b = blockIdx.x;

    if (b < NB_GEMM) {
        // ----------------- GEMM role (MFMA bf16, R12-exact) ----------------
        const int tile = b >> 3;      // 0..127
        const int ks   = b & 7;       // 0..7
        const int m0 = tile * 64;
        const int k_begin = ks * KCHUNK;
        const int k_end   = (k_begin + KCHUNK < NFEAT) ? k_begin + KCHUNK : NFEAT;
        const int l = t & 63;
        const int w = t >> 6;

        const int sr  = t >> 2;
        const int sc8 = (t & 3) * 8;
        const float* xrow = x + (size_t)(m0 + sr) * NFEAT;
        const int wc  = t & 63;
        const int wk8 = (t >> 6) * 8;
        const int arow = w * 16 + (l & 15);
        const int kb   = (l >> 4) * 8;

        f32x4 acc[4];
        #pragma unroll
        for (int ct = 0; ct < 4; ++ct) acc[ct] = (f32x4){0.f, 0.f, 0.f, 0.f};

        for (int k0 = k_begin; k0 < k_end; k0 += 32) {
            uint4 xp;
            {
                ushort u[8];
                #pragma unroll
                for (int jj = 0; jj < 8; ++jj) {
                    int k = k0 + sc8 + jj;
                    u[jj] = f2bf((k < k_end) ? xrow[k] : 0.f);
                }
                xp.x = (unsigned)u[0] | ((unsigned)u[1] << 16);
                xp.y = (unsigned)u[2] | ((unsigned)u[3] << 16);
                xp.z = (unsigned)u[4] | ((unsigned)u[5] << 16);
                xp.w = (unsigned)u[6] | ((unsigned)u[7] << 16);
            }
            *(uint4*)(&xa[sr][sc8]) = xp;
            uint4 wp;
            {
                ushort u[8];
                #pragma unroll
                for (int jj = 0; jj < 8; ++jj) {
                    int k = k0 + wk8 + jj;
                    u[jj] = f2bf((k < k_end) ? W1[(size_t)k * 64 + wc] : 0.f);
                }
                wp.x = (unsigned)u[0] | ((unsigned)u[1] << 16);
                wp.y = (unsigned)u[2] | ((unsigned)u[3] << 16);
                wp.z = (unsigned)u[4] | ((unsigned)u[5] << 16);
                wp.w = (unsigned)u[6] | ((unsigned)u[7] << 16);
            }
            *(uint4*)(&wt[wc][wk8]) = wp;
            __syncthreads();

            bf16x8 af = *(const bf16x8*)(&xa[arow][kb]);
            #pragma unroll
            for (int ct = 0; ct < 4; ++ct) {
                bf16x8 bfr = *(const bf16x8*)(&wt[ct * 16 + (l & 15)][kb]);
                acc[ct] = __builtin_amdgcn_mfma_f32_16x16x32_bf16(af, bfr, acc[ct], 0, 0, 0);
            }
            __syncthreads();
        }
        float* pout = part + (size_t)ks * NN * NHID;
        const int orow = m0 + w * 16 + ((l >> 4) << 2);
        const int ocol = l & 15;
        #pragma unroll
        for (int ct = 0; ct < 4; ++ct)
            #pragma unroll
            for (int rix = 0; rix < 4; ++rix)
                pout[(size_t)(orow + rix) * 64 + ct * 16 + ocol] = acc[ct][rix];
    } else {
        // ----------------- triangle scan role: 1 row per wave --------------
        const int wave = t >> 6;
        const int lane = t & 63;
        const int bid  = b - NB_GEMM;           // 0..2047
        const int row  = bid * 4 + wave;        // ascending (R12 exact)
        scan_row(row, adj, bmq, lane);
    }
}

// ---------------------------------------------------------------------------
// K2: csr role (2048 blocks) || reduce role (512 blocks). R12-exact.
// ---------------------------------------------------------------------------
__global__ __launch_bounds__(256) void k2_csr_reduce(const unsigned long long* __restrict__ bmq,
                                                     const float* __restrict__ P,
                                                     const float* __restrict__ part,
                                                     int* __restrict__ cnt,
                                                     int* __restrict__ cols,
                                                     float* __restrict__ vals,
                                                     float* __restrict__ dinv,
                                                     float* __restrict__ XW1) {
    const int b = blockIdx.x;
    if (b >= NB_CSR) {
        const size_t i4 = (size_t)(b - NB_CSR) * 256 + threadIdx.x;
        const f32x4* p4 = (const f32x4*)part;
        f32x4 s = p4[i4];
        #pragma unroll
        for (int ks = 1; ks < KSPLIT; ++ks)
            s += p4[(size_t)ks * (NN * NHID / 4) + i4];
        ((f32x4*)XW1)[i4] = s;
        return;
    }
    const int wave = threadIdx.x >> 6;
    const int lane = threadIdx.x & 63;
    const int row  = b * 4 + wave;

    const unsigned long long* rw = bmq + (size_t)row * 128;
    unsigned long long w0 = rw[2 * lane];
    unsigned long long w1 = rw[2 * lane + 1];
    const int myc = __popcll(w0) + __popcll(w1);

    int incl = myc;
    #pragma unroll
    for (int ofs = 1; ofs < 64; ofs <<= 1) {
        int y = __shfl_up(incl, ofs, 64);
        if (lane >= ofs) incl += y;
    }
    const int total = __shfl(incl, 63, 64);
    int pos = incl - myc;

    const size_t rowCAP = (size_t)row * CAP;
    float dsum = 0.f;
    #pragma unroll
    for (int i = 0; i < 2; ++i) {
        unsigned long long w = i ? w1 : w0;
        const int widx = 2 * lane + i;
        const int Cl = widx >> 2, s = widx & 3;
        const int colbase = 256 * Cl + s;
        while (w) {
            int j = __builtin_ctzll(w);
            w &= w - 1;
            int col = colbase + 4 * j;
            unsigned lo = (col <= row) ? (unsigned)col : (unsigned)row;
            unsigned hi = (col <= row) ? (unsigned)row : (unsigned)col;
            unsigned pidx = hi * (hi + 1u) / 2u + lo;
            float p = P[pidx];
            float v = 1.f / (1.f + __expf(-p));
            if (pos < CAP) {
                cols[rowCAP + pos] = col;
                vals[rowCAP + pos] = v;
            }
            dsum += v;
            ++pos;
        }
    }
    #pragma unroll
    for (int s2 = 32; s2; s2 >>= 1) dsum += __shfl_xor(dsum, s2, 64);
    if (lane == 0) {
        cnt[row]  = (total < CAP) ? total : CAP;
        dinv[row] = 1.f / sqrtf(1.f + dsum);
    }
}

// ---------------------------------------------------------------------------
// spmm1 (unchanged)
// ---------------------------------------------------------------------------
__global__ __launch_bounds__(256) void k_spmm1(const float* __restrict__ XW1,
                                               const float* __restrict__ dinv,
                                               const int* __restrict__ cnt,
                                               const int* __restrict__ cols,
                                               const float* __restrict__ vals,
                                               const float* __restrict__ b1,
                                               const float* __restrict__ W2,
                                               float* __restrict__ HW2) {
    const int wave = threadIdx.x >> 6;
    const int lane = threadIdx.x & 63;
    const int row  = blockIdx.x * 4 + wave;
    if (row >= NN) return;

    const float di = dinv[row];
    float acc = di * XW1[(size_t)row * NHID + lane];
    const int c = cnt[row];
    const int*   cp = cols + (size_t)row * CAP;
    const float* vp = vals + (size_t)row * CAP;

    int j0 = 0, j1 = 0; float v0 = 0.f, v1 = 0.f, w0 = 0.f, w1 = 0.f, d0 = 0.f, d1 = 0.f;
    if (c > 0) { j0 = cp[0]; v0 = vp[0]; w0 = XW1[(size_t)j0 * NHID + lane]; d0 = dinv[j0]; }
    if (c > 1) { j1 = cp[1]; v1 = vp[1]; w1 = XW1[(size_t)j1 * NHID + lane]; d1 = dinv[j1]; }
    for (int k = 0; k < c; ++k) {
        acc += v0 * d0 * w0;
        j0 = j1; v0 = v1; w0 = w1; d0 = d1;
        if (k + 2 < c) {
            int jn = cp[k + 2];
            j1 = jn; v1 = vp[k + 2];
            w1 = XW1[(size_t)jn * NHID + lane];
            d1 = dinv[jn];
        }
    }
    float h1 = di * acc + b1[lane];
    h1 = fmaxf(h1, 0.f);

    float o[NCLASS];
    #pragma unroll
    for (int cc = 0; cc < NCLASS; ++cc) o[cc] = h1 * W2[lane * NCLASS + cc];
    #pragma unroll
    for (int cc = 0; cc < NCLASS; ++cc)
        for (int s = 32; s; s >>= 1) o[cc] += __shfl_xor(o[cc], s, 64);
    if (lane == 0) {
        #pragma unroll
        for (int cc = 0; cc < NCLASS; ++cc)
            HW2[(size_t)row * NCLASS + cc] = o[cc];
    }
}

// ---------------------------------------------------------------------------
// spmm2 (unchanged)
// ---------------------------------------------------------------------------
__global__ __launch_bounds__(256) void k_spmm2(const float* __restrict__ HW2,
                                               const float* __restrict__ dinv,
                                               const int* __restrict__ cnt,
                                               const int* __restrict__ cols,
                                               const float* __restrict__ vals,
                                               const float* __restrict__ b2,
                                               float* __restrict__ out) {
    const int wave = threadIdx.x >> 6;
    const int lane = threadIdx.x & 63;
    const int row  = blockIdx.x * 4 + wave;
    if (row >= NN) return;

    const int c = cnt[row];
    const int*   cp = cols + (size_t)row * CAP;
    const float* vp = vals + (size_t)row * CAP;
    float acc[NCLASS] = {};
    for (int k = lane; k < c; k += 64) {
        int j   = cp[k];
        float wgt = vp[k] * dinv[j];
        #pragma unroll
        for (int cc = 0; cc < NCLASS; ++cc)
            acc[cc] += wgt * HW2[(size_t)j * NCLASS + cc];
    }
    #pragma unroll
    for (int cc = 0; cc < NCLASS; ++cc)
        for (int s = 32; s; s >>= 1) acc[cc] += __shfl_xor(acc[cc], s, 64);

    if (lane == 0) {
        const float di = dinv[row];
        float h[NCLASS], m = -1e30f;
        #pragma unroll
        for (int cc = 0; cc < NCLASS; ++cc) {
            h[cc] = di * (acc[cc] + di * HW2[(size_t)row * NCLASS + cc]) + b2[cc];
            m = fmaxf(m, h[cc]);
        }
        float s = 0.f;
        #pragma unroll
        for (int cc = 0; cc < NCLASS; ++cc) s += expf(h[cc] - m);
        float lse = m + logf(s);
        #pragma unroll
        for (int cc = 0; cc < NCLASS; ++cc)
            out[(size_t)row * NCLASS + cc] = h[cc] - lse;
    }
}

// ---------------------------------------------------------------------------
extern "C" void kernel_launch(void* const* d_in, const int* in_sizes, int n_in,
                              void* d_out, int out_size, void* d_ws, size_t ws_size,
                              hipStream_t stream) {
    const float* x   = (const float*)d_in[0];
    const float* adj = (const float*)d_in[1];
    const float* P   = (const float*)d_in[2];
    const float* W1  = (const float*)d_in[3];
    const float* b1  = (const float*)d_in[4];
    const float* W2  = (const float*)d_in[5];
    const float* b2  = (const float*)d_in[6];
    float* out = (float*)d_out;

    char* ws = (char*)d_ws;
    size_t off = 0;
    float* dinv = (float*)(ws + off);  off += (size_t)NN * 4;
    int*   cnt  = (int*)  (ws + off);  off += (size_t)NN * 4;
    int*   cols = (int*)  (ws + off);  off += (size_t)NN * CAP * 4;
    float* vals = (float*)(ws + off);  off += (size_t)NN * CAP * 4;
    float* XW1  = (float*)(ws + off);  off += (size_t)NN * NHID * 4;
    float* HW2  = (float*)(ws + off);  off += (size_t)NN * NCLASS * 4;
    float* part = (float*)(ws + off);  off += (size_t)KSPLIT * NN * NHID * 4;
    off = (off + 255) & ~(size_t)255;
    unsigned long long* bmq = (unsigned long long*)(ws + off);
    off += (size_t)NN * 128 * 8;   // 8 MB bitmask

    k_zero<<<dim3(2048), dim3(256), 0, stream>>>((uint4*)bmq);
    k1_scan_gemm<<<dim3(NB_GEMM + NB_SCAN), dim3(256), 0, stream>>>(adj, x, W1, bmq, part);
    k2_csr_reduce<<<dim3(NB_CSR + NB_RED), dim3(256), 0, stream>>>(bmq, P, part,
                                                                   cnt, cols, vals, dinv, XW1);
    k_spmm1<<<dim3(NN / 4), dim3(256), 0, stream>>>(XW1, dinv, cnt, cols, vals, b1, W2, HW2);
    k_spmm2<<<dim3(NN / 4), dim3(256), 0, stream>>>(HW2, dinv, cnt, cols, vals, b2, out);
}